// Round 1
// baseline (605.796 us; speedup 1.0000x reference)
//
#include <hip/hip_runtime.h>

#define N_NODES 100000
#define N_EDGES 1600000
#define NB_N 391  // ceil(N_NODES/256)

// ---------------- degree / normalization ----------------

__global__ __launch_bounds__(256) void k_degree(const int* __restrict__ src,
                                                const int* __restrict__ dst,
                                                unsigned* __restrict__ dout,
                                                unsigned* __restrict__ din) {
  int e = blockIdx.x * 256 + threadIdx.x;
  if (e < N_EDGES) {
    atomicAdd(&dout[src[e]], 1u);
    atomicAdd(&din[dst[e]], 1u);
  }
}

__global__ __launch_bounds__(256) void k_isqrt(const unsigned* __restrict__ dout,
                                               const unsigned* __restrict__ din,
                                               float* __restrict__ oi,
                                               float* __restrict__ ii) {
  int i = blockIdx.x * 256 + threadIdx.x;
  if (i < N_NODES) {
    unsigned a = dout[i]; if (a < 1u) a = 1u;
    unsigned b = din[i];  if (b < 1u) b = 1u;
    oi[i] = rsqrtf((float)a);
    ii[i] = rsqrtf((float)b);
  }
}

// ---------------- CSR build: 3-pass scan + fill ----------------

__global__ __launch_bounds__(256) void k_scan1(const unsigned* __restrict__ din,
                                               unsigned* __restrict__ partials) {
  __shared__ unsigned sd[256];
  int t = threadIdx.x;
  int i = blockIdx.x * 256 + t;
  sd[t] = (i < N_NODES) ? din[i] : 0u;
  __syncthreads();
  for (int s = 128; s > 0; s >>= 1) {
    if (t < s) sd[t] += sd[t + s];
    __syncthreads();
  }
  if (t == 0) partials[blockIdx.x] = sd[0];
}

__global__ __launch_bounds__(512) void k_scan2(const unsigned* __restrict__ partials,
                                               unsigned* __restrict__ poff) {
  __shared__ unsigned sd[512];
  int t = threadIdx.x;
  unsigned v = (t < NB_N) ? partials[t] : 0u;
  sd[t] = v;
  __syncthreads();
  for (int d = 1; d < 512; d <<= 1) {
    unsigned a = (t >= d) ? sd[t - d] : 0u;
    __syncthreads();
    sd[t] += a;
    __syncthreads();
  }
  if (t < NB_N) poff[t] = sd[t] - v;  // exclusive
}

__global__ __launch_bounds__(256) void k_scan3(const unsigned* __restrict__ din,
                                               const unsigned* __restrict__ poff,
                                               int* __restrict__ row_ptr,
                                               int* __restrict__ cursor) {
  __shared__ unsigned sd[256];
  int t = threadIdx.x;
  int i = blockIdx.x * 256 + t;
  unsigned v = (i < N_NODES) ? din[i] : 0u;
  sd[t] = v;
  __syncthreads();
  for (int d = 1; d < 256; d <<= 1) {
    unsigned a = (t >= d) ? sd[t - d] : 0u;
    __syncthreads();
    sd[t] += a;
    __syncthreads();
  }
  if (i < N_NODES) {
    int r = (int)(poff[blockIdx.x] + sd[t] - v);
    row_ptr[i] = r;
    cursor[i] = r;
  }
  if (i == 0) row_ptr[N_NODES] = N_EDGES;
}

__global__ __launch_bounds__(256) void k_fill(const int* __restrict__ src,
                                              const int* __restrict__ dst,
                                              int* __restrict__ cursor,
                                              int* __restrict__ csr_src) {
  int e = blockIdx.x * 256 + threadIdx.x;
  if (e < N_EDGES) {
    int d = dst[e];
    int slot = atomicAdd(&cursor[d], 1);
    csr_src[slot] = src[e];
  }
}

// ---------------- GEMM1: h1 = (x * oi) @ W1  (100k x 128 x 128) ----------------
// block: 256 thr, 32 rows/block. LDS: W k-tile 64x128 (32KB) + X 32x68 (8.5KB)
// thread (c4 = t&31 -> 4 cols, rg = t>>5 -> 4 rows): 4x4 float4 accumulators.

__global__ __launch_bounds__(256) void k_gemm1(const float* __restrict__ x,
                                               const float* __restrict__ oi,
                                               const float* __restrict__ W,
                                               float* __restrict__ h) {
  __shared__ float Ws[64 * 128];
  __shared__ float Xs[32 * 68];
  const int t = threadIdx.x;
  const int row0 = blockIdx.x * 32;
  const int c4 = t & 31;
  const int rg = t >> 5;
  float4 acc[4];
#pragma unroll
  for (int i = 0; i < 4; ++i) acc[i] = make_float4(0.f, 0.f, 0.f, 0.f);

  for (int kt = 0; kt < 128; kt += 64) {
#pragma unroll
    for (int j = 0; j < 8; ++j) {
      int q = t + 256 * j;
      int kk = q >> 5, cc = q & 31;
      *(float4*)(Ws + kk * 128 + 4 * cc) =
          *(const float4*)(W + (kt + kk) * 128 + 4 * cc);
    }
#pragma unroll
    for (int j = 0; j < 2; ++j) {
      int q = t + 256 * j;  // 0..511, 16 chunks per row
      int r = q >> 4, kc = q & 15;
      float4 v = *(const float4*)(x + (size_t)(row0 + r) * 128 + kt + 4 * kc);
      float s = oi[row0 + r];
      v.x *= s; v.y *= s; v.z *= s; v.w *= s;
      *(float4*)(Xs + r * 68 + 4 * kc) = v;
    }
    __syncthreads();
#pragma unroll 4
    for (int kq = 0; kq < 16; ++kq) {
      float4 xv[4];
#pragma unroll
      for (int i = 0; i < 4; ++i)
        xv[i] = *(const float4*)(Xs + (rg * 4 + i) * 68 + 4 * kq);
#pragma unroll
      for (int kk = 0; kk < 4; ++kk) {
        float4 wv = *(const float4*)(Ws + (kq * 4 + kk) * 128 + 4 * c4);
#pragma unroll
        for (int i = 0; i < 4; ++i) {
          float xc = ((const float*)&xv[i])[kk];
          acc[i].x = fmaf(xc, wv.x, acc[i].x);
          acc[i].y = fmaf(xc, wv.y, acc[i].y);
          acc[i].z = fmaf(xc, wv.z, acc[i].z);
          acc[i].w = fmaf(xc, wv.w, acc[i].w);
        }
      }
    }
    __syncthreads();
  }
#pragma unroll
  for (int i = 0; i < 4; ++i)
    *(float4*)(h + (size_t)(row0 + rg * 4 + i) * 128 + 4 * c4) = acc[i];
}

// ---------------- AGG1: h1a[n] = ii[n] * sum_{e: dst=n} h1[src_e]  (128 ch) ----------------
// 32 lanes per node, float4 per lane; CSR loop, no atomics.

__global__ __launch_bounds__(256) void k_agg1(const float* __restrict__ h1,
                                              const int* __restrict__ csr_src,
                                              const int* __restrict__ row_ptr,
                                              const float* __restrict__ ii,
                                              float* __restrict__ out) {
  const int t = threadIdx.x;
  const int node = blockIdx.x * 8 + (t >> 5);
  const int c = t & 31;
  const int beg = row_ptr[node];
  const int end = row_ptr[node + 1];
  float4 acc = make_float4(0.f, 0.f, 0.f, 0.f);
  for (int j = beg; j < end; ++j) {
    int s = csr_src[j];
    float4 v = *(const float4*)(h1 + (size_t)s * 128 + 4 * c);
    acc.x += v.x; acc.y += v.y; acc.z += v.z; acc.w += v.w;
  }
  float sc = ii[node];
  acc.x *= sc; acc.y *= sc; acc.z *= sc; acc.w *= sc;
  *(float4*)(out + (size_t)node * 128 + 4 * c) = acc;
}

// ---------------- GEMM2: h2 = (relu(h1a) * oi) @ W2  (100k x 128 x 40) ----------------
// block: 256 thr, 32 rows/block; c4 = t&15 (only c4<10 active -> 40 cols), rg = t>>4 -> 2 rows.

__global__ __launch_bounds__(256) void k_gemm2(const float* __restrict__ g,
                                               const float* __restrict__ oi,
                                               const float* __restrict__ W2,
                                               float* __restrict__ h2) {
  __shared__ float Ws[128 * 40];
  __shared__ float Xs[32 * 132];
  const int t = threadIdx.x;
  const int row0 = blockIdx.x * 32;
  const int c4 = t & 15;
  const int rg = t >> 4;
#pragma unroll
  for (int j = 0; j < 5; ++j) {
    int q = t + 256 * j;  // < 1280 float4 chunks
    int k = q / 10, cc = q % 10;
    *(float4*)(Ws + k * 40 + 4 * cc) = *(const float4*)(W2 + k * 40 + 4 * cc);
  }
#pragma unroll
  for (int j = 0; j < 4; ++j) {
    int q = t + 256 * j;
    int r = q >> 5, kc = q & 31;
    float4 v = *(const float4*)(g + (size_t)(row0 + r) * 128 + 4 * kc);
    float s = oi[row0 + r];
    v.x = fmaxf(v.x, 0.f) * s;
    v.y = fmaxf(v.y, 0.f) * s;
    v.z = fmaxf(v.z, 0.f) * s;
    v.w = fmaxf(v.w, 0.f) * s;
    *(float4*)(Xs + r * 132 + 4 * kc) = v;
  }
  __syncthreads();
  if (c4 < 10) {
    float4 a0 = make_float4(0.f, 0.f, 0.f, 0.f);
    float4 a1 = make_float4(0.f, 0.f, 0.f, 0.f);
#pragma unroll 4
    for (int kq = 0; kq < 32; ++kq) {
      float4 x0 = *(const float4*)(Xs + (rg * 2) * 132 + 4 * kq);
      float4 x1 = *(const float4*)(Xs + (rg * 2 + 1) * 132 + 4 * kq);
#pragma unroll
      for (int kk = 0; kk < 4; ++kk) {
        float4 wv = *(const float4*)(Ws + (kq * 4 + kk) * 40 + 4 * c4);
        float xc0 = ((const float*)&x0)[kk];
        float xc1 = ((const float*)&x1)[kk];
        a0.x = fmaf(xc0, wv.x, a0.x);
        a0.y = fmaf(xc0, wv.y, a0.y);
        a0.z = fmaf(xc0, wv.z, a0.z);
        a0.w = fmaf(xc0, wv.w, a0.w);
        a1.x = fmaf(xc1, wv.x, a1.x);
        a1.y = fmaf(xc1, wv.y, a1.y);
        a1.z = fmaf(xc1, wv.z, a1.z);
        a1.w = fmaf(xc1, wv.w, a1.w);
      }
    }
    *(float4*)(h2 + (size_t)(row0 + rg * 2) * 40 + 4 * c4) = a0;
    *(float4*)(h2 + (size_t)(row0 + rg * 2 + 1) * 40 + 4 * c4) = a1;
  }
}

// ---------------- AGG2: out[n] = ii[n] * sum h2[src_e]  (40 ch) ----------------
// 16 lanes per node, lanes 0..9 carry one float4 each.

__global__ __launch_bounds__(256) void k_agg2(const float* __restrict__ h2,
                                              const int* __restrict__ csr_src,
                                              const int* __restrict__ row_ptr,
                                              const float* __restrict__ ii,
                                              float* __restrict__ out) {
  const int t = threadIdx.x;
  const int node = blockIdx.x * 16 + (t >> 4);
  const int c = t & 15;
  if (c < 10) {
    const int beg = row_ptr[node];
    const int end = row_ptr[node + 1];
    float4 acc = make_float4(0.f, 0.f, 0.f, 0.f);
    for (int j = beg; j < end; ++j) {
      int s = csr_src[j];
      float4 v = *(const float4*)(h2 + (size_t)s * 40 + 4 * c);
      acc.x += v.x; acc.y += v.y; acc.z += v.z; acc.w += v.w;
    }
    float sc = ii[node];
    acc.x *= sc; acc.y *= sc; acc.z *= sc; acc.w *= sc;
    *(float4*)(out + (size_t)node * 40 + 4 * c) = acc;
  }
}

// ---------------- launch ----------------

extern "C" void kernel_launch(void* const* d_in, const int* in_sizes, int n_in,
                              void* d_out, int out_size, void* d_ws, size_t ws_size,
                              hipStream_t stream) {
  const float* x  = (const float*)d_in[0];
  const int* ei   = (const int*)d_in[1];
  const float* W1 = (const float*)d_in[2];
  const float* W2 = (const float*)d_in[3];
  const int* src = ei;
  const int* dst = ei + N_EDGES;
  float* out = (float*)d_out;

  char* p = (char*)d_ws;
  auto alloc = [&](size_t b) -> void* {
    char* r = p;
    p += (b + 255) & ~(size_t)255;
    return (void*)r;
  };
  unsigned* deg_out  = (unsigned*)alloc((size_t)N_NODES * 4);
  unsigned* deg_in   = (unsigned*)alloc((size_t)N_NODES * 4);
  int* row_ptr       = (int*)alloc((size_t)(N_NODES + 1) * 4);
  int* cursor        = (int*)alloc((size_t)N_NODES * 4);
  float* oi          = (float*)alloc((size_t)N_NODES * 4);
  float* ii          = (float*)alloc((size_t)N_NODES * 4);
  unsigned* partials = (unsigned*)alloc((size_t)NB_N * 4);
  unsigned* poff     = (unsigned*)alloc((size_t)NB_N * 4);
  int* csr_src       = (int*)alloc((size_t)N_EDGES * 4);
  float* h1          = (float*)alloc((size_t)N_NODES * 128 * 4);
  float* h1a         = (float*)alloc((size_t)N_NODES * 128 * 4);
  float* h2          = (float*)alloc((size_t)N_NODES * 40 * 4);

  hipMemsetAsync(deg_out, 0, (size_t)N_NODES * 4, stream);
  hipMemsetAsync(deg_in, 0, (size_t)N_NODES * 4, stream);
  k_degree<<<N_EDGES / 256, 256, 0, stream>>>(src, dst, deg_out, deg_in);
  k_isqrt<<<NB_N, 256, 0, stream>>>(deg_out, deg_in, oi, ii);
  k_scan1<<<NB_N, 256, 0, stream>>>(deg_in, partials);
  k_scan2<<<1, 512, 0, stream>>>(partials, poff);
  k_scan3<<<NB_N, 256, 0, stream>>>(deg_in, poff, row_ptr, cursor);
  k_fill<<<N_EDGES / 256, 256, 0, stream>>>(src, dst, cursor, csr_src);
  k_gemm1<<<N_NODES / 32, 256, 0, stream>>>(x, oi, W1, h1);
  k_agg1<<<N_NODES / 8, 256, 0, stream>>>(h1, csr_src, row_ptr, ii, h1a);
  k_gemm2<<<N_NODES / 32, 256, 0, stream>>>(h1a, oi, W2, h2);
  k_agg2<<<N_NODES / 16, 256, 0, stream>>>(h2, csr_src, row_ptr, ii, out);
}